// Round 5
// baseline (745.888 us; speedup 1.0000x reference)
//
#include <hip/hip_runtime.h>
#include <cmath>
#include <cstdint>

#pragma clang fp contract(off)

#define B_ 2
#define N_ 65536
#define M_ 128
#define K_ 2048
#define S_ 6
#define NBLK 256          /* classify/compact blocks per batch */
#define CT 256            /* classify/compact threads per block */
#define FPS_T 512         /* threads per FPS chain (8 waves) */
#define PAIR_T 1024       /* two chains fused per block */
#define NW 8              /* waves per chain */
#define RMAX 8            /* per-thread point slots */
#define CAP (FPS_T * RMAX)  /* 4096 points max per chain for register path */

#define PI_F 3.14159265358979323846f
#define SS_F 1.0471975511965976f   /* (float)(2.0*pi/6) */

// Wave-wide max of 64-bit keys via DPP (VALU latency, not DS latency).
// Lane 63 holds the result. Identity: key==0 (bound_ctrl zero-fill loses).
__device__ __forceinline__ unsigned long long wave_max_u64_dpp(unsigned long long key) {
#define DPP_STEP(CTRL)                                                          \
    {                                                                           \
        unsigned lo = (unsigned)key, hi = (unsigned)(key >> 32);                \
        unsigned olo = (unsigned)__builtin_amdgcn_update_dpp(0, (int)lo, CTRL, 0xf, 0xf, true); \
        unsigned ohi = (unsigned)__builtin_amdgcn_update_dpp(0, (int)hi, CTRL, 0xf, 0xf, true); \
        unsigned long long o = ((unsigned long long)ohi << 32) | olo;           \
        if (o > key) key = o;                                                   \
    }
    DPP_STEP(0x111)  /* row_shr:1  */
    DPP_STEP(0x112)  /* row_shr:2  */
    DPP_STEP(0x114)  /* row_shr:4  */
    DPP_STEP(0x118)  /* row_shr:8  */
    DPP_STEP(0x142)  /* row_bcast:15 */
    DPP_STEP(0x143)  /* row_bcast:31 */
#undef DPP_STEP
    return key;
}

// ------------------------------------------------------------ classify ----
__global__ __launch_bounds__(CT)
void k_classify(const float* __restrict__ points, const float* __restrict__ rois,
                int* __restrict__ sec_id, int* __restrict__ blkcnt) {
    __shared__ float4 sroi[M_];
    __shared__ int lc[8];
    int blk = blockIdx.x;
    int gid = blk * CT + threadIdx.x;
    int b = gid >> 16;                       // N_ = 65536
    if (threadIdx.x < M_) {
        const float* r = rois + ((size_t)b * M_ + threadIdx.x) * 7;
        float cz = r[2] + r[5] * 0.5f;       // geometric center
        float hx = r[3] * 0.5f, hy = r[4] * 0.5f, hz = r[5] * 0.5f;
        sroi[threadIdx.x] = make_float4(r[0], r[1], cz, sqrtf((hx*hx + hy*hy) + hz*hz));
    }
    if (threadIdx.x < 8) lc[threadIdx.x] = 0;
    __syncthreads();

    const float* p = points + (size_t)gid * 3;
    float px = p[0], py = p[1], pz = p[2];
    float best = 1e30f; int bi = 0;
    for (int m = 0; m < M_; m++) {
        float4 c = sroi[m];
        float dx = px - c.x, dy = py - c.y, dz = pz - c.z;
        float d = sqrtf((dx*dx + dy*dy) + dz*dz);
        if (d < best) { best = d; bi = m; }  // strict < : first argmin
    }
    bool valid = best < (sroi[bi].w + 1.6f);

    float a = atan2f(py, px) + PI_F;
    float fs = floorf(a / SS_F);
    fs = fminf(fmaxf(fs, 0.0f), 6.0f);
    int sec = (int)fs;

    sec_id[gid] = valid ? sec : -1;
    if (valid) atomicAdd(&lc[sec], 1);
    __syncthreads();
    if (threadIdx.x < 8) blkcnt[blk * 8 + threadIdx.x] = lc[threadIdx.x];
}

// ---------------------------------------------------------------- plan ----
__global__ void k_plan(const int* __restrict__ blkcnt, int* __restrict__ bbase,
                       int* __restrict__ cnt, int* __restrict__ offv,
                       int* __restrict__ n_needed, int* __restrict__ sec_base,
                       int* __restrict__ s_total) {
    __shared__ int scnt[2][8];
    int t = threadIdx.x;
    if (t < 16) scnt[t >> 3][t & 7] = 0;
    __syncthreads();
    if (t < 14) {
        int b = t / 7, s = t % 7;
        int run = 0;
        #pragma unroll 16
        for (int j = 0; j < NBLK; j++) {
            int blk = b * NBLK + j;
            int c = blkcnt[blk * 8 + s];
            if (s < 6) bbase[blk * 6 + s] = run;
            run += c;
        }
        scnt[b][s] = run;
        cnt[b * 8 + s] = run;
    }
    __syncthreads();
    if (t < B_) {
        int b = t;
        int total = 0;
        for (int s = 0; s < 7; s++) total += scnt[b][s];
        if (total < 1) total = 1;
        int sb = 0, snk = 0;
        for (int s = 0; s < 6; s++) {
            int cs = scnt[b][s];
            int nk = (int)ceilf((float)cs * 2048.0f / (float)total);  // f32 semantics
            if (nk > cs) nk = cs;
            offv[b * 6 + s] = snk;
            int need = 0;
            if (snk < K_) { need = K_ - snk; if (need > nk) need = nk; }
            n_needed[b * 6 + s] = need;
            sec_base[b * 6 + s] = sb;
            sb += cs; snk += nk;
        }
        s_total[b] = (snk < 1) ? 1 : snk;
    }
}

// ------------------------------------------------------------- compact ----
__global__ __launch_bounds__(CT)
void k_compact(const float* __restrict__ points, const int* __restrict__ sec_id,
               const int* __restrict__ sec_base, const int* __restrict__ bbase,
               int* __restrict__ comp_idx, float4* __restrict__ comp_xyz) {
    __shared__ int lc[4 * 6];
    __shared__ int sbase[6], blkb[6];
    int blk = blockIdx.x;
    int b = blk >> 8;                         // NBLK = 256 blocks per batch
    int tid = threadIdx.x, lane = tid & 63, wid = tid >> 6;
    if (tid < 6) sbase[tid] = sec_base[b * 6 + tid];
    else if (tid >= 64 && tid < 70) blkb[tid - 64] = bbase[blk * 6 + (tid - 64)];
    int gid = blk * CT + tid;
    int sec = sec_id[gid];
    unsigned long long mymask = 0;
    for (int s = 0; s < 6; s++) {
        unsigned long long m = __ballot(sec == s);
        if (sec == s) mymask = m;
        if (lane == 0) lc[wid * 6 + s] = __popcll(m);
    }
    __syncthreads();
    if (sec >= 0 && sec < 6) {
        int woff = 0;
        for (int w = 0; w < wid; w++) woff += lc[w * 6 + sec];
        int rank = __popcll(mymask & ((1ull << lane) - 1ull));
        int addr = b * N_ + sbase[sec] + blkb[sec] + woff + rank;
        const float* p = points + (size_t)gid * 3;
        comp_idx[addr] = gid & (N_ - 1);
        comp_xyz[addr] = make_float4(p[0], p[1], p[2], 0.0f);
    }
}

// ----------------------------------------------------------------- fps ----
// TWO independent FPS chains per block (1024 thr = 2 x 8 waves), but with
// NO shared barrier in the pick loop: round 4 proved __syncthreads
// phase-locks the halves (per-CU VALU issue stayed 57% while work doubled
// -> 2x duration). Each half syncs its own 8 waves with an LDS
// sense-protocol: lane63 writes skey -> fence -> atomicAdd arrival; the
// 8th arriver resets the counter, fences, and stores the monotonic
// release srel[half]=k; all lanes spin on srel>=k (volatile), then a
// compiler barrier, then the round-3 tree + sxyz[bix] broadcast. Halves
// free-run and de-phase, so one half's slot-loop issue fills the other
// half's reduce-latency bubbles on the same SIMDs.
// Safety: skey double-buffer (par=k&1) reuse at k+2 is gated by release
// k+1, which needs all arrivals at k+1, each after that wave read pick
// k's keys -> race-free. All 8 waves of a half run the same need -> no
// lost arrivals -> no deadlock. Each wave's lane0 writes pick_lds[k]
// (same value) so writeback needs no final sync (same-wave LDS order).
// Per-half math is byte-identical to round 3 -> picks bit-exact.
__global__ __launch_bounds__(PAIR_T)
void k_fps(const int* __restrict__ cnt, const int* __restrict__ sec_base,
           const int* __restrict__ offv, const int* __restrict__ n_needed,
           const float4* __restrict__ comp_xyz,
           float* __restrict__ dmin_g, int* __restrict__ buf) {
    __shared__ float4 sxyz[2][CAP];                 // 128 KB
    __shared__ int pick_lds[2][K_];                 // 16 KB
    __shared__ unsigned long long skey[2][2][NW];   // 256 B
    __shared__ int scount[2][2];
    __shared__ int srel[2];
    int tid = threadIdx.x;
    int half = tid >> 9;                  // 0: chain c0, 1: chain c1
    int ltid = tid & (FPS_T - 1);
    int lane = tid & 63;
    int w8 = (tid >> 6) & 7;              // wave index within half

    int c0 = blockIdx.x, c1 = blockIdx.x + S_;      // pair across batches
    int chain = half ? c1 : c0;
    int b = chain / S_, s = chain % S_;
    int need = n_needed[b * 6 + s];
    int cs = cnt[b * 8 + s];
    int base = b * N_ + sec_base[b * 6 + s];
    const float4* cxyz = comp_xyz + base;
    int off = b * K_ + offv[b * 6 + s];
    float* dm = dmin_g + base;
    bool fast = (cs <= CAP);              // uniform within half

    if (ltid < 2) scount[half][ltid] = 0;
    if (ltid == 0) ((volatile int*)srel)[half] = 0;
    if (lane == 0) pick_lds[half][0] = 0;  // every wave: first pick = 0

    // ---- stage points into registers + LDS mirror (fast path) ----
    float px[RMAX], py[RMAX], pz[RMAX], dmv[RMAX];
    if (fast && need > 0) {
        #pragma unroll
        for (int r = 0; r < RMAX; r++) {
            if (r * FPS_T < cs) {
                int i = ltid + r * FPS_T;
                if (i < cs) {
                    float4 q = cxyz[i];
                    sxyz[half][i] = q;
                    px[r] = q.x; py[r] = q.y; pz[r] = q.z;
                    dmv[r] = 1e10f;
                }
            }
        }
    }
    __syncthreads();   // ONLY block-wide sync: staging + protocol init

    if (need > 0) {
        float lx, ly, lz;
        if (fast) { float4 l4 = sxyz[half][0]; lx = l4.x; ly = l4.y; lz = l4.z; }
        else      { float4 l4 = cxyz[0];       lx = l4.x; ly = l4.y; lz = l4.z; }

        #pragma unroll 1
        for (int k = 1; k < need; k++) {
            unsigned long long key = 0;
            if (fast) {
                unsigned long long t[4] = {0ull, 0ull, 0ull, 0ull};
                #pragma unroll
                for (int r = 0; r < RMAX; r++) {
                    if (r * FPS_T < cs) {          // wave-uniform
                        int i = ltid + r * FPS_T;
                        if (i < cs) {
                            float dx = px[r] - lx, dy = py[r] - ly, dz = pz[r] - lz;
                            float d = (dx*dx + dy*dy) + dz*dz;    // contract off
                            float nd = fminf(dmv[r], d);
                            dmv[r] = nd;
                            unsigned long long kk =
                                ((unsigned long long)__float_as_uint(nd) << 32)
                                | (unsigned)(~(unsigned)i);
                            if (kk > t[r & 3]) t[r & 3] = kk;     // 4 parallel chains
                        }
                    }
                }
                unsigned long long ta = (t[1] > t[0]) ? t[1] : t[0];
                unsigned long long tb = (t[3] > t[2]) ? t[3] : t[2];
                key = (tb > ta) ? tb : ta;
            } else {
                // fallback: dmin in global (not taken for this data: cs<=CAP)
                #pragma unroll 1
                for (int i = ltid; i < cs; i += FPS_T) {
                    float4 q = cxyz[i];
                    float dx = q.x - lx, dy = q.y - ly, dz = q.z - lz;
                    float d = (dx*dx + dy*dy) + dz*dz;
                    float prev = (k == 1) ? 1e10f : dm[i];
                    float nd = fminf(prev, d);
                    dm[i] = nd;
                    unsigned long long kk =
                        ((unsigned long long)__float_as_uint(nd) << 32)
                        | (unsigned)(~(unsigned)i);
                    if (kk > key) key = kk;
                }
            }
            key = wave_max_u64_dpp(key);
            int par = k & 1;
            // ---- per-half sense sync: arrive ----
            if (lane == 63) {
                skey[half][par][w8] = key;
                __threadfence_block();                 // skey visible first
                int old = atomicAdd(&scount[half][par], 1);
                if (old == NW - 1) {                   // last arriver
                    ((volatile int*)scount)[half * 2 + par] = 0;
                    __threadfence_block();             // reset before release
                    ((volatile int*)srel)[half] = k;   // monotonic release
                }
            }
            while (((volatile int*)srel)[half] < k) {} // spin (per half)
            __asm__ __volatile__("" ::: "memory");     // no hoisting past spin
            // ---- reduce over 8 wave keys ----
            unsigned long long q0 = skey[half][par][0], q1 = skey[half][par][1];
            unsigned long long q2 = skey[half][par][2], q3 = skey[half][par][3];
            unsigned long long q4 = skey[half][par][4], q5 = skey[half][par][5];
            unsigned long long q6 = skey[half][par][6], q7 = skey[half][par][7];
            q0 = (q1 > q0) ? q1 : q0;
            q2 = (q3 > q2) ? q3 : q2;
            q4 = (q5 > q4) ? q5 : q4;
            q6 = (q7 > q6) ? q7 : q6;
            q0 = (q2 > q0) ? q2 : q0;
            q4 = (q6 > q4) ? q6 : q4;
            unsigned long long bk = (q4 > q0) ? q4 : q0;
            int bix = (int)(~(unsigned)(bk & 0xFFFFFFFFull));
            if (lane == 0) pick_lds[half][k] = bix;    // every wave, same value
            if (fast) {
                float4 n4 = sxyz[half][bix];           // LDS broadcast
                lx = n4.x; ly = n4.y; lz = n4.z;
            } else {
                float4 n4 = cxyz[bix];                 // rare path
                lx = n4.x; ly = n4.y; lz = n4.z;
            }
        }
        // coalesced writeback of all picks (per half; same-wave LDS order
        // guarantees this wave's lane0 writes are visible to its lanes)
        #pragma unroll 1
        for (int i = ltid; i < need; i += FPS_T)
            buf[off + i] = base + pick_lds[half][i];
    }
}

// ----------------------------------------------------------------- out ----
__global__ void k_out(const float* __restrict__ points, const int* __restrict__ buf,
                      const int* __restrict__ comp_idx, const int* __restrict__ s_total,
                      float* __restrict__ out) {
    int i = blockIdx.x * 256 + threadIdx.x;
    if (i >= B_ * K_) return;
    int b = i / K_, j = i % K_;
    int st = s_total[b];
    int g = buf[b * K_ + (j % st)];          // compacted global slot
    int idx = comp_idx[g];                   // original point index
    const float* p = points + ((size_t)b * N_ + idx) * 3;
    float* o = out + (size_t)i * 3;
    o[0] = p[0]; o[1] = p[1]; o[2] = p[2];
}

// -------------------------------------------------------------- launch ----
extern "C" void kernel_launch(void* const* d_in, const int* in_sizes, int n_in,
                              void* d_out, int out_size, void* d_ws, size_t ws_size,
                              hipStream_t stream) {
    const float* points = (const float*)d_in[0];   // [B,N,3]
    const float* rois   = (const float*)d_in[1];   // [B,M,7]
    float* out = (float*)d_out;                    // [B,K,3]

    char* w = (char*)d_ws;
    auto carve = [&](size_t bytes) -> char* {
        char* p = w; w += (bytes + 255) & ~(size_t)255; return p;
    };
    int*    sec_id   = (int*)   carve((size_t)B_ * N_ * sizeof(int));
    int*    blkcnt   = (int*)   carve((size_t)B_ * NBLK * 8 * sizeof(int));
    int*    bbase    = (int*)   carve((size_t)B_ * NBLK * 6 * sizeof(int));
    int*    cnt      = (int*)   carve((size_t)B_ * 8 * sizeof(int));
    int*    offv     = (int*)   carve((size_t)B_ * 6 * sizeof(int));
    int*    n_needed = (int*)   carve((size_t)B_ * 6 * sizeof(int));
    int*    sec_base = (int*)   carve((size_t)B_ * 6 * sizeof(int));
    int*    s_total  = (int*)   carve((size_t)B_ * sizeof(int));
    int*    buf      = (int*)   carve((size_t)B_ * K_ * sizeof(int));
    int*    comp_idx = (int*)   carve((size_t)B_ * N_ * sizeof(int));
    float4* comp_xyz = (float4*)carve((size_t)B_ * N_ * sizeof(float4));
    float*  dmin_g   = (float*) carve((size_t)B_ * N_ * sizeof(float));

    hipLaunchKernelGGL(k_classify, dim3(B_ * NBLK), dim3(CT), 0, stream,
                       points, rois, sec_id, blkcnt);
    hipLaunchKernelGGL(k_plan, dim3(1), dim3(64), 0, stream,
                       blkcnt, bbase, cnt, offv, n_needed, sec_base, s_total);
    hipLaunchKernelGGL(k_compact, dim3(B_ * NBLK), dim3(CT), 0, stream,
                       points, sec_id, sec_base, bbase, comp_idx, comp_xyz);
    hipLaunchKernelGGL(k_fps, dim3((B_ * S_) / 2), dim3(PAIR_T), 0, stream,
                       cnt, sec_base, offv, n_needed, comp_xyz, dmin_g, buf);
    hipLaunchKernelGGL(k_out, dim3((B_ * K_ + 255) / 256), dim3(256), 0, stream,
                       points, buf, comp_idx, s_total, out);
}

// Round 7
// 517.860 us; speedup vs baseline: 1.4403x; 1.4403x over previous
//
#include <hip/hip_runtime.h>
#include <cmath>
#include <cstdint>

#pragma clang fp contract(off)

#define B_ 2
#define N_ 65536
#define M_ 128
#define K_ 2048
#define S_ 6
#define NBLK 256          /* classify/compact blocks per batch */
#define CT 256            /* classify/compact threads per block */
#define FPS_T 512         /* 8 waves: 2 waves/SIMD */
#define NW 8              /* FPS_T / 64 waves */
#define RMAX 8            /* per-thread point slots */
#define NPAIR (RMAX / 2)  /* packed f32 pairs per thread */
#define CAP (FPS_T * RMAX)  /* 4096 points max for register fast path */

#define PI_F 3.14159265358979323846f
#define SS_F 1.0471975511965976f   /* (float)(2.0*pi/6) */

typedef float f2 __attribute__((ext_vector_type(2)));

// Dual-pumped packed f32 (CDNA3+; gfx950's 157.3TF peak requires these).
// Element-wise with default VOP3P modifiers; IEEE-identical to scalar ops.
__device__ __forceinline__ f2 pk_add(f2 a, f2 b) {
    f2 d; asm("v_pk_add_f32 %0, %1, %2" : "=v"(d) : "v"(a), "v"(b)); return d;
}
__device__ __forceinline__ f2 pk_mul(f2 a, f2 b) {
    f2 d; asm("v_pk_mul_f32 %0, %1, %2" : "=v"(d) : "v"(a), "v"(b)); return d;
}

// Wave-wide max of 64-bit keys via DPP (VALU latency, not DS latency).
// Lane 63 holds the result. Identity: key==0 (bound_ctrl zero-fill loses).
__device__ __forceinline__ unsigned long long wave_max_u64_dpp(unsigned long long key) {
#define DPP_STEP(CTRL)                                                          \
    {                                                                           \
        unsigned lo = (unsigned)key, hi = (unsigned)(key >> 32);                \
        unsigned olo = (unsigned)__builtin_amdgcn_update_dpp(0, (int)lo, CTRL, 0xf, 0xf, true); \
        unsigned ohi = (unsigned)__builtin_amdgcn_update_dpp(0, (int)hi, CTRL, 0xf, 0xf, true); \
        unsigned long long o = ((unsigned long long)ohi << 32) | olo;           \
        if (o > key) key = o;                                                   \
    }
    DPP_STEP(0x111)  /* row_shr:1  */
    DPP_STEP(0x112)  /* row_shr:2  */
    DPP_STEP(0x114)  /* row_shr:4  */
    DPP_STEP(0x118)  /* row_shr:8  */
    DPP_STEP(0x142)  /* row_bcast:15 */
    DPP_STEP(0x143)  /* row_bcast:31 */
#undef DPP_STEP
    return key;
}

// ------------------------------------------------------------ classify ----
__global__ __launch_bounds__(CT)
void k_classify(const float* __restrict__ points, const float* __restrict__ rois,
                int* __restrict__ sec_id, int* __restrict__ blkcnt) {
    __shared__ float4 sroi[M_];
    __shared__ int lc[8];
    int blk = blockIdx.x;
    int gid = blk * CT + threadIdx.x;
    int b = gid >> 16;                       // N_ = 65536
    if (threadIdx.x < M_) {
        const float* r = rois + ((size_t)b * M_ + threadIdx.x) * 7;
        float cz = r[2] + r[5] * 0.5f;       // geometric center
        float hx = r[3] * 0.5f, hy = r[4] * 0.5f, hz = r[5] * 0.5f;
        sroi[threadIdx.x] = make_float4(r[0], r[1], cz, sqrtf((hx*hx + hy*hy) + hz*hz));
    }
    if (threadIdx.x < 8) lc[threadIdx.x] = 0;
    __syncthreads();

    const float* p = points + (size_t)gid * 3;
    float px = p[0], py = p[1], pz = p[2];
    float best = 1e30f; int bi = 0;
    for (int m = 0; m < M_; m++) {
        float4 c = sroi[m];
        float dx = px - c.x, dy = py - c.y, dz = pz - c.z;
        float d = sqrtf((dx*dx + dy*dy) + dz*dz);
        if (d < best) { best = d; bi = m; }  // strict < : first argmin
    }
    bool valid = best < (sroi[bi].w + 1.6f);

    float a = atan2f(py, px) + PI_F;
    float fs = floorf(a / SS_F);
    fs = fminf(fmaxf(fs, 0.0f), 6.0f);
    int sec = (int)fs;

    sec_id[gid] = valid ? sec : -1;
    if (valid) atomicAdd(&lc[sec], 1);
    __syncthreads();
    if (threadIdx.x < 8) blkcnt[blk * 8 + threadIdx.x] = lc[threadIdx.x];
}

// ---------------------------------------------------------------- plan ----
__global__ void k_plan(const int* __restrict__ blkcnt, int* __restrict__ bbase,
                       int* __restrict__ cnt, int* __restrict__ offv,
                       int* __restrict__ n_needed, int* __restrict__ sec_base,
                       int* __restrict__ s_total) {
    __shared__ int scnt[2][8];
    int t = threadIdx.x;
    if (t < 16) scnt[t >> 3][t & 7] = 0;
    __syncthreads();
    if (t < 14) {
        int b = t / 7, s = t % 7;
        int run = 0;
        #pragma unroll 16
        for (int j = 0; j < NBLK; j++) {
            int blk = b * NBLK + j;
            int c = blkcnt[blk * 8 + s];
            if (s < 6) bbase[blk * 6 + s] = run;
            run += c;
        }
        scnt[b][s] = run;
        cnt[b * 8 + s] = run;
    }
    __syncthreads();
    if (t < B_) {
        int b = t;
        int total = 0;
        for (int s = 0; s < 7; s++) total += scnt[b][s];
        if (total < 1) total = 1;
        int sb = 0, snk = 0;
        for (int s = 0; s < 6; s++) {
            int cs = scnt[b][s];
            int nk = (int)ceilf((float)cs * 2048.0f / (float)total);  // f32 semantics
            if (nk > cs) nk = cs;
            offv[b * 6 + s] = snk;
            int need = 0;
            if (snk < K_) { need = K_ - snk; if (need > nk) need = nk; }
            n_needed[b * 6 + s] = need;
            sec_base[b * 6 + s] = sb;
            sb += cs; snk += nk;
        }
        s_total[b] = (snk < 1) ? 1 : snk;
    }
}

// ------------------------------------------------------------- compact ----
__global__ __launch_bounds__(CT)
void k_compact(const float* __restrict__ points, const int* __restrict__ sec_id,
               const int* __restrict__ sec_base, const int* __restrict__ bbase,
               int* __restrict__ comp_idx, float4* __restrict__ comp_xyz) {
    __shared__ int lc[4 * 6];
    __shared__ int sbase[6], blkb[6];
    int blk = blockIdx.x;
    int b = blk >> 8;                         // NBLK = 256 blocks per batch
    int tid = threadIdx.x, lane = tid & 63, wid = tid >> 6;
    if (tid < 6) sbase[tid] = sec_base[b * 6 + tid];
    else if (tid >= 64 && tid < 70) blkb[tid - 64] = bbase[blk * 6 + (tid - 64)];
    int gid = blk * CT + tid;
    int sec = sec_id[gid];
    unsigned long long mymask = 0;
    for (int s = 0; s < 6; s++) {
        unsigned long long m = __ballot(sec == s);
        if (sec == s) mymask = m;
        if (lane == 0) lc[wid * 6 + s] = __popcll(m);
    }
    __syncthreads();
    if (sec >= 0 && sec < 6) {
        int woff = 0;
        for (int w = 0; w < wid; w++) woff += lc[w * 6 + sec];
        int rank = __popcll(mymask & ((1ull << lane) - 1ull));
        int addr = b * N_ + sbase[sec] + blkb[sec] + woff + rank;
        const float* p = points + (size_t)gid * 3;
        comp_idx[addr] = gid & (N_ - 1);
        comp_xyz[addr] = make_float4(p[0], p[1], p[2], 0.0f);
    }
}

// ----------------------------------------------------------------- fps ----
// one block (512 thr, 8 waves = 2/SIMD) per (b,s) — the verified round-3
// structure. Rounds 4/5 proved the pick period is ~86% ISSUE-limited
// (co-located chains split throughput exactly 2-way; stall is only
// ~300-500cy/pick), so this round cuts per-pick instructions:
//  (1) packed f32 (v_pk_add/v_pk_mul) for the distance math — IEEE
//      bit-identical to the scalar sequence (a+(-b)==a-b, no contraction),
//      ~halves the FP op count;
//  (2) sentinel padding at STAGING (i>=cs -> xyz=0, dmv=0 -> key (0,~i)
//      always loses: real nd>0 wins on hi word; real nd==0 wins on ~i
//      since i_real < cs <= i_sent) removes ALL per-lane slot predication
//      from the pick loop — only the cheap wave-uniform pair guard stays.
// Reduce path unchanged from round 3: 4 u64 max chains + tree, key-only
// DPP wave argmax, lane63 -> skey, ONE barrier, 8-key tree, dependent
// sxyz[bix] LDS broadcast. Keys unique (embedded ~i) -> any reduction
// order is bit-exact. ZERO global memory ops inside the pick loop.
__global__ __launch_bounds__(FPS_T, 2)
void k_fps(const int* __restrict__ cnt, const int* __restrict__ sec_base,
           const int* __restrict__ offv, const int* __restrict__ n_needed,
           const float4* __restrict__ comp_xyz,
           float* __restrict__ dmin_g, int* __restrict__ buf) {
    __shared__ float4 sxyz[CAP];
    __shared__ int pick_lds[K_];
    __shared__ unsigned long long skey[2][NW];
    int b = blockIdx.x / S_, s = blockIdx.x % S_;
    int need = n_needed[b * 6 + s];
    if (need <= 0) return;
    int cs = cnt[b * 8 + s];
    int base = b * N_ + sec_base[b * 6 + s];
    const float4* cxyz = comp_xyz + base;
    int off = b * K_ + offv[b * 6 + s];
    int tid = threadIdx.x, lane = tid & 63, wid = tid >> 6;
    unsigned ni = ~(unsigned)tid;

    if (cs <= CAP) {
        // ---- fast path: packed points + dmin in registers, sentinel pad ----
        f2 px2[NPAIR], py2[NPAIR], pz2[NPAIR];
        float dmv[RMAX];
        #pragma unroll
        for (int q = 0; q < NPAIR; q++) {
            int i0 = tid + (2 * q) * FPS_T;
            int i1 = i0 + FPS_T;
            float4 a = make_float4(0.0f, 0.0f, 0.0f, 0.0f);
            float4 c = make_float4(0.0f, 0.0f, 0.0f, 0.0f);
            float d0 = 0.0f, d1 = 0.0f;
            if (i0 < cs) { a = cxyz[i0]; sxyz[i0] = a; d0 = 1e10f; }
            if (i1 < cs) { c = cxyz[i1]; sxyz[i1] = c; d1 = 1e10f; }
            px2[q] = (f2){a.x, c.x};
            py2[q] = (f2){a.y, c.y};
            pz2[q] = (f2){a.z, c.z};
            dmv[2 * q] = d0; dmv[2 * q + 1] = d1;
        }
        if (tid == 0) pick_lds[0] = 0;       // first pick = first point
        __syncthreads();
        float4 l4 = sxyz[0];
        float lx = l4.x, ly = l4.y, lz = l4.z;

        #pragma unroll 1
        for (int k = 1; k < need; k++) {
            f2 nlx = (f2){-lx, -lx};
            f2 nly = (f2){-ly, -ly};
            f2 nlz = (f2){-lz, -lz};
            unsigned long long t[4] = {0ull, 0ull, 0ull, 0ull};
            #pragma unroll
            for (int q = 0; q < NPAIR; q++) {
                if (q * (2 * FPS_T) < cs) {          // wave-uniform guard only
                    f2 dx = pk_add(px2[q], nlx);     // px + (-lx) == px - lx
                    f2 dy = pk_add(py2[q], nly);
                    f2 dz = pk_add(pz2[q], nlz);
                    f2 ss = pk_add(pk_add(pk_mul(dx, dx), pk_mul(dy, dy)),
                                   pk_mul(dz, dz));  // (dx*dx+dy*dy)+dz*dz
                    float nd0 = fminf(dmv[2 * q],     ss.x);
                    float nd1 = fminf(dmv[2 * q + 1], ss.y);
                    dmv[2 * q] = nd0; dmv[2 * q + 1] = nd1;
                    unsigned long long k0 =
                        ((unsigned long long)__float_as_uint(nd0) << 32)
                        | (unsigned)(ni - (2 * q) * FPS_T);       // == ~i0
                    unsigned long long k1 =
                        ((unsigned long long)__float_as_uint(nd1) << 32)
                        | (unsigned)(ni - (2 * q + 1) * FPS_T);   // == ~i1
                    int c0 = (q & 1) * 2, c1 = c0 + 1;            // 4 chains
                    if (k0 > t[c0]) t[c0] = k0;
                    if (k1 > t[c1]) t[c1] = k1;
                }
            }
            unsigned long long ta = (t[1] > t[0]) ? t[1] : t[0];
            unsigned long long tb = (t[3] > t[2]) ? t[3] : t[2];
            unsigned long long key = (tb > ta) ? tb : ta;
            key = wave_max_u64_dpp(key);
            int par = k & 1;
            if (lane == 63) skey[par][wid] = key;
            __syncthreads();
            unsigned long long q0 = skey[par][0], q1 = skey[par][1];
            unsigned long long q2 = skey[par][2], q3 = skey[par][3];
            unsigned long long q4 = skey[par][4], q5 = skey[par][5];
            unsigned long long q6 = skey[par][6], q7 = skey[par][7];
            q0 = (q1 > q0) ? q1 : q0;
            q2 = (q3 > q2) ? q3 : q2;
            q4 = (q5 > q4) ? q5 : q4;
            q6 = (q7 > q6) ? q7 : q6;
            q0 = (q2 > q0) ? q2 : q0;
            q4 = (q6 > q4) ? q6 : q4;
            unsigned long long bk = (q4 > q0) ? q4 : q0;
            int bix = (int)(~(unsigned)(bk & 0xFFFFFFFFull));
            if (tid == 0) pick_lds[k] = bix;                  // LDS, not global
            float4 n4 = sxyz[bix];                            // LDS broadcast
            lx = n4.x; ly = n4.y; lz = n4.z;
        }
        __syncthreads();
        // coalesced writeback of all picks
        #pragma unroll 1
        for (int i = tid; i < need; i += FPS_T)
            buf[off + i] = base + pick_lds[i];
    } else {
        // ---- fallback: dmin in global (not taken for this data: cs<=CAP) ----
        float* dm = dmin_g + base;
        if (tid == 0) pick_lds[0] = 0;
        __syncthreads();
        float4 f0 = cxyz[0];
        float lx = f0.x, ly = f0.y, lz = f0.z;
        #pragma unroll 1
        for (int k = 1; k < need; k++) {
            unsigned long long key = 0;
            #pragma unroll 1
            for (int i = tid; i < cs; i += FPS_T) {
                float4 q = cxyz[i];
                float dx = q.x - lx, dy = q.y - ly, dz = q.z - lz;
                float d = (dx*dx + dy*dy) + dz*dz;
                float prev = (k == 1) ? 1e10f : dm[i];
                float nd = fminf(prev, d);
                dm[i] = nd;
                unsigned long long kk =
                    ((unsigned long long)__float_as_uint(nd) << 32) | (unsigned)(~(unsigned)i);
                if (kk > key) key = kk;
            }
            key = wave_max_u64_dpp(key);
            int par = k & 1;
            if (lane == 63) skey[par][wid] = key;
            __syncthreads();
            unsigned long long q0 = skey[par][0], q1 = skey[par][1];
            unsigned long long q2 = skey[par][2], q3 = skey[par][3];
            unsigned long long q4 = skey[par][4], q5 = skey[par][5];
            unsigned long long q6 = skey[par][6], q7 = skey[par][7];
            q0 = (q1 > q0) ? q1 : q0;
            q2 = (q3 > q2) ? q3 : q2;
            q4 = (q5 > q4) ? q5 : q4;
            q6 = (q7 > q6) ? q7 : q6;
            q0 = (q2 > q0) ? q2 : q0;
            q4 = (q6 > q4) ? q6 : q4;
            unsigned long long bk = (q4 > q0) ? q4 : q0;
            int bix = (int)(~(unsigned)(bk & 0xFFFFFFFFull));
            if (tid == 0) pick_lds[k] = bix;
            float4 n4 = cxyz[bix];                            // rare path
            lx = n4.x; ly = n4.y; lz = n4.z;
        }
        __syncthreads();
        #pragma unroll 1
        for (int i = tid; i < need; i += FPS_T)
            buf[off + i] = base + pick_lds[i];
    }
}

// ----------------------------------------------------------------- out ----
__global__ void k_out(const float* __restrict__ points, const int* __restrict__ buf,
                      const int* __restrict__ comp_idx, const int* __restrict__ s_total,
                      float* __restrict__ out) {
    int i = blockIdx.x * 256 + threadIdx.x;
    if (i >= B_ * K_) return;
    int b = i / K_, j = i % K_;
    int st = s_total[b];
    int g = buf[b * K_ + (j % st)];          // compacted global slot
    int idx = comp_idx[g];                   // original point index
    const float* p = points + ((size_t)b * N_ + idx) * 3;
    float* o = out + (size_t)i * 3;
    o[0] = p[0]; o[1] = p[1]; o[2] = p[2];
}

// -------------------------------------------------------------- launch ----
extern "C" void kernel_launch(void* const* d_in, const int* in_sizes, int n_in,
                              void* d_out, int out_size, void* d_ws, size_t ws_size,
                              hipStream_t stream) {
    const float* points = (const float*)d_in[0];   // [B,N,3]
    const float* rois   = (const float*)d_in[1];   // [B,M,7]
    float* out = (float*)d_out;                    // [B,K,3]

    char* w = (char*)d_ws;
    auto carve = [&](size_t bytes) -> char* {
        char* p = w; w += (bytes + 255) & ~(size_t)255; return p;
    };
    int*    sec_id   = (int*)   carve((size_t)B_ * N_ * sizeof(int));
    int*    blkcnt   = (int*)   carve((size_t)B_ * NBLK * 8 * sizeof(int));
    int*    bbase    = (int*)   carve((size_t)B_ * NBLK * 6 * sizeof(int));
    int*    cnt      = (int*)   carve((size_t)B_ * 8 * sizeof(int));
    int*    offv     = (int*)   carve((size_t)B_ * 6 * sizeof(int));
    int*    n_needed = (int*)   carve((size_t)B_ * 6 * sizeof(int));
    int*    sec_base = (int*)   carve((size_t)B_ * 6 * sizeof(int));
    int*    s_total  = (int*)   carve((size_t)B_ * sizeof(int));
    int*    buf      = (int*)   carve((size_t)B_ * K_ * sizeof(int));
    int*    comp_idx = (int*)   carve((size_t)B_ * N_ * sizeof(int));
    float4* comp_xyz = (float4*)carve((size_t)B_ * N_ * sizeof(float4));
    float*  dmin_g   = (float*) carve((size_t)B_ * N_ * sizeof(float));

    hipLaunchKernelGGL(k_classify, dim3(B_ * NBLK), dim3(CT), 0, stream,
                       points, rois, sec_id, blkcnt);
    hipLaunchKernelGGL(k_plan, dim3(1), dim3(64), 0, stream,
                       blkcnt, bbase, cnt, offv, n_needed, sec_base, s_total);
    hipLaunchKernelGGL(k_compact, dim3(B_ * NBLK), dim3(CT), 0, stream,
                       points, sec_id, sec_base, bbase, comp_idx, comp_xyz);
    hipLaunchKernelGGL(k_fps, dim3(B_ * S_), dim3(FPS_T), 0, stream,
                       cnt, sec_base, offv, n_needed, comp_xyz, dmin_g, buf);
    hipLaunchKernelGGL(k_out, dim3((B_ * K_ + 255) / 256), dim3(256), 0, stream,
                       points, buf, comp_idx, s_total, out);
}

// Round 8
// 468.947 us; speedup vs baseline: 1.5906x; 1.1043x over previous
//
#include <hip/hip_runtime.h>
#include <cmath>
#include <cstdint>

#pragma clang fp contract(off)

#define B_ 2
#define N_ 65536
#define M_ 128
#define K_ 2048
#define S_ 6
#define NBLK 256          /* classify/compact blocks per batch */
#define CT 256            /* classify/compact threads per block */
#define FPS_T 512         /* 8 waves: 2 waves/SIMD */
#define NW 8              /* FPS_T / 64 waves */
#define RMAX 8            /* per-thread point slots */
#define CAP (FPS_T * RMAX)  /* 4096 points max for register fast path */

#define PI_F 3.14159265358979323846f
#define SS_F 1.0471975511965976f   /* (float)(2.0*pi/6) */

// Wave-wide max of 64-bit keys via DPP (VALU latency, not DS latency).
// Lane 63 holds the result. Identity: key==0 (bound_ctrl zero-fill loses).
__device__ __forceinline__ unsigned long long wave_max_u64_dpp(unsigned long long key) {
#define DPP_STEP(CTRL)                                                          \
    {                                                                           \
        unsigned lo = (unsigned)key, hi = (unsigned)(key >> 32);                \
        unsigned olo = (unsigned)__builtin_amdgcn_update_dpp(0, (int)lo, CTRL, 0xf, 0xf, true); \
        unsigned ohi = (unsigned)__builtin_amdgcn_update_dpp(0, (int)hi, CTRL, 0xf, 0xf, true); \
        unsigned long long o = ((unsigned long long)ohi << 32) | olo;           \
        if (o > key) key = o;                                                   \
    }
    DPP_STEP(0x111)  /* row_shr:1  */
    DPP_STEP(0x112)  /* row_shr:2  */
    DPP_STEP(0x114)  /* row_shr:4  */
    DPP_STEP(0x118)  /* row_shr:8  */
    DPP_STEP(0x142)  /* row_bcast:15 */
    DPP_STEP(0x143)  /* row_bcast:31 */
#undef DPP_STEP
    return key;
}

// ------------------------------------------------------------ classify ----
__global__ __launch_bounds__(CT)
void k_classify(const float* __restrict__ points, const float* __restrict__ rois,
                int* __restrict__ sec_id, int* __restrict__ blkcnt) {
    __shared__ float4 sroi[M_];
    __shared__ int lc[8];
    int blk = blockIdx.x;
    int gid = blk * CT + threadIdx.x;
    int b = gid >> 16;                       // N_ = 65536
    if (threadIdx.x < M_) {
        const float* r = rois + ((size_t)b * M_ + threadIdx.x) * 7;
        float cz = r[2] + r[5] * 0.5f;       // geometric center
        float hx = r[3] * 0.5f, hy = r[4] * 0.5f, hz = r[5] * 0.5f;
        sroi[threadIdx.x] = make_float4(r[0], r[1], cz, sqrtf((hx*hx + hy*hy) + hz*hz));
    }
    if (threadIdx.x < 8) lc[threadIdx.x] = 0;
    __syncthreads();

    const float* p = points + (size_t)gid * 3;
    float px = p[0], py = p[1], pz = p[2];
    float best = 1e30f; int bi = 0;
    for (int m = 0; m < M_; m++) {
        float4 c = sroi[m];
        float dx = px - c.x, dy = py - c.y, dz = pz - c.z;
        float d = sqrtf((dx*dx + dy*dy) + dz*dz);
        if (d < best) { best = d; bi = m; }  // strict < : first argmin
    }
    bool valid = best < (sroi[bi].w + 1.6f);

    float a = atan2f(py, px) + PI_F;
    float fs = floorf(a / SS_F);
    fs = fminf(fmaxf(fs, 0.0f), 6.0f);
    int sec = (int)fs;

    sec_id[gid] = valid ? sec : -1;
    if (valid) atomicAdd(&lc[sec], 1);
    __syncthreads();
    if (threadIdx.x < 8) blkcnt[blk * 8 + threadIdx.x] = lc[threadIdx.x];
}

// ---------------------------------------------------------------- plan ----
__global__ void k_plan(const int* __restrict__ blkcnt, int* __restrict__ bbase,
                       int* __restrict__ cnt, int* __restrict__ offv,
                       int* __restrict__ n_needed, int* __restrict__ sec_base,
                       int* __restrict__ s_total) {
    __shared__ int scnt[2][8];
    int t = threadIdx.x;
    if (t < 16) scnt[t >> 3][t & 7] = 0;
    __syncthreads();
    if (t < 14) {
        int b = t / 7, s = t % 7;
        int run = 0;
        #pragma unroll 16
        for (int j = 0; j < NBLK; j++) {
            int blk = b * NBLK + j;
            int c = blkcnt[blk * 8 + s];
            if (s < 6) bbase[blk * 6 + s] = run;
            run += c;
        }
        scnt[b][s] = run;
        cnt[b * 8 + s] = run;
    }
    __syncthreads();
    if (t < B_) {
        int b = t;
        int total = 0;
        for (int s = 0; s < 7; s++) total += scnt[b][s];
        if (total < 1) total = 1;
        int sb = 0, snk = 0;
        for (int s = 0; s < 6; s++) {
            int cs = scnt[b][s];
            int nk = (int)ceilf((float)cs * 2048.0f / (float)total);  // f32 semantics
            if (nk > cs) nk = cs;
            offv[b * 6 + s] = snk;
            int need = 0;
            if (snk < K_) { need = K_ - snk; if (need > nk) need = nk; }
            n_needed[b * 6 + s] = need;
            sec_base[b * 6 + s] = sb;
            sb += cs; snk += nk;
        }
        s_total[b] = (snk < 1) ? 1 : snk;
    }
}

// ------------------------------------------------------------- compact ----
__global__ __launch_bounds__(CT)
void k_compact(const float* __restrict__ points, const int* __restrict__ sec_id,
               const int* __restrict__ sec_base, const int* __restrict__ bbase,
               int* __restrict__ comp_idx, float4* __restrict__ comp_xyz) {
    __shared__ int lc[4 * 6];
    __shared__ int sbase[6], blkb[6];
    int blk = blockIdx.x;
    int b = blk >> 8;                         // NBLK = 256 blocks per batch
    int tid = threadIdx.x, lane = tid & 63, wid = tid >> 6;
    if (tid < 6) sbase[tid] = sec_base[b * 6 + tid];
    else if (tid >= 64 && tid < 70) blkb[tid - 64] = bbase[blk * 6 + (tid - 64)];
    int gid = blk * CT + tid;
    int sec = sec_id[gid];
    unsigned long long mymask = 0;
    for (int s = 0; s < 6; s++) {
        unsigned long long m = __ballot(sec == s);
        if (sec == s) mymask = m;
        if (lane == 0) lc[wid * 6 + s] = __popcll(m);
    }
    __syncthreads();
    if (sec >= 0 && sec < 6) {
        int woff = 0;
        for (int w = 0; w < wid; w++) woff += lc[w * 6 + sec];
        int rank = __popcll(mymask & ((1ull << lane) - 1ull));
        int addr = b * N_ + sbase[sec] + blkb[sec] + woff + rank;
        const float* p = points + (size_t)gid * 3;
        comp_idx[addr] = gid & (N_ - 1);
        comp_xyz[addr] = make_float4(p[0], p[1], p[2], 0.0f);
    }
}

// ----------------------------------------------------------------- fps ----
// one block (512 thr, 8 waves = 2/SIMD) per (b,s) — round-3 structure with
// a shorter reduce tail. r7 showed v_pk_f32 is issue-neutral on gfx950
// (VALU-cycles equal) and hurts scheduling; r4/r5 showed pairing chains
// can never help wall time (12 chains already on 12 CUs; wall = longest
// chain). The ~1000cy/pick tail was: lane63 ds_write -> barrier ->
// 8x ds_read_b64 + 21-op u64 tree (ALL 512 threads, redundant) ->
// dependent sxyz[bix] read. This round:
//  (1) cross-wave reduce via LDS atomicMax (ds_max_u64) into a single
//      slot: 8 same-address atomics pre-barrier (overlap wave skew);
//      post-barrier = ONE ds_read_b64 + ~lo -> bix -> sxyz[bix].
//      3-slot rotation, tid0 resets slot[(k+1)%3]; any reset at pick k is
//      separated from that slot's last readers (pick k-2) by barrier k-1
//      -> race-free. u64 max is order-free; keys embed ~i -> bit-exact,
//      ties (hi=0: picked-duplicates/sentinels) resolve to min global i,
//      matching reference argmax-first.
//  (2) sentinel staging (i>=cs -> xyz=0, dmv=0; key (0,~i) always loses:
//      real nd>0 wins on hi word, real nd==0 wins on ~i since i<cs)
//      removes per-slot exec-mask predication; scalar math unchanged.
// ZERO global memory ops in the pick loop; writeback batched at end.
__global__ __launch_bounds__(FPS_T, 2)
void k_fps(const int* __restrict__ cnt, const int* __restrict__ sec_base,
           const int* __restrict__ offv, const int* __restrict__ n_needed,
           const float4* __restrict__ comp_xyz,
           float* __restrict__ dmin_g, int* __restrict__ buf) {
    __shared__ float4 sxyz[CAP];
    __shared__ int pick_lds[K_];
    __shared__ unsigned long long skey[2][NW];   // fallback path only
    __shared__ unsigned long long slotA[3];      // rotating atomic-max slots
    int b = blockIdx.x / S_, s = blockIdx.x % S_;
    int need = n_needed[b * 6 + s];
    if (need <= 0) return;
    int cs = cnt[b * 8 + s];
    int base = b * N_ + sec_base[b * 6 + s];
    const float4* cxyz = comp_xyz + base;
    int off = b * K_ + offv[b * 6 + s];
    int tid = threadIdx.x, lane = tid & 63, wid = tid >> 6;

    if (cs <= CAP) {
        // ---- fast path: points + dmin in registers, sentinel-padded ----
        float px[RMAX], py[RMAX], pz[RMAX], dmv[RMAX];
        #pragma unroll
        for (int r = 0; r < RMAX; r++) {
            int i = tid + r * FPS_T;
            float4 q = make_float4(0.0f, 0.0f, 0.0f, 0.0f);
            float d0 = 0.0f;
            if (i < cs) { q = cxyz[i]; sxyz[i] = q; d0 = 1e10f; }
            px[r] = q.x; py[r] = q.y; pz[r] = q.z; dmv[r] = d0;
        }
        if (tid < 3) slotA[tid] = 0ull;
        if (tid == 0) pick_lds[0] = 0;       // first pick = first point
        __syncthreads();
        float4 l4 = sxyz[0];
        float lx = l4.x, ly = l4.y, lz = l4.z;

        int cur = 1;                          // k % 3, starting at k=1
        #pragma unroll 1
        for (int k = 1; k < need; k++) {
            unsigned long long t[4] = {0ull, 0ull, 0ull, 0ull};
            #pragma unroll
            for (int r = 0; r < RMAX; r++) {
                if (r * FPS_T < cs) {        // wave-uniform guard only
                    int i = tid + r * FPS_T;
                    float dx = px[r] - lx, dy = py[r] - ly, dz = pz[r] - lz;
                    float d = (dx*dx + dy*dy) + dz*dz;    // contract off
                    float nd = fminf(dmv[r], d);
                    dmv[r] = nd;
                    unsigned long long kk =
                        ((unsigned long long)__float_as_uint(nd) << 32)
                        | (unsigned)(~(unsigned)i);
                    if (kk > t[r & 3]) t[r & 3] = kk;     // 4 parallel chains
                }
            }
            unsigned long long ta = (t[1] > t[0]) ? t[1] : t[0];
            unsigned long long tb = (t[3] > t[2]) ? t[3] : t[2];
            unsigned long long key = (tb > ta) ? tb : ta;
            key = wave_max_u64_dpp(key);
            int nxt = (cur == 2) ? 0 : cur + 1;
            if (lane == 63) atomicMax(&slotA[cur], key);   // ds_max_u64 x8
            if (tid == 0) slotA[nxt] = 0ull;               // reset for k+1
            __syncthreads();
            unsigned long long bk = slotA[cur];            // ONE broadcast read
            int bix = (int)(~(unsigned)(bk & 0xFFFFFFFFull));
            if (tid == 0) pick_lds[k] = bix;               // LDS, not global
            float4 n4 = sxyz[bix];                         // LDS broadcast
            lx = n4.x; ly = n4.y; lz = n4.z;
            cur = nxt;
        }
        __syncthreads();
        // coalesced writeback of all picks
        #pragma unroll 1
        for (int i = tid; i < need; i += FPS_T)
            buf[off + i] = base + pick_lds[i];
    } else {
        // ---- fallback: dmin in global (not taken for this data: cs<=CAP) ----
        float* dm = dmin_g + base;
        if (tid == 0) pick_lds[0] = 0;
        __syncthreads();
        float4 f0 = cxyz[0];
        float lx = f0.x, ly = f0.y, lz = f0.z;
        #pragma unroll 1
        for (int k = 1; k < need; k++) {
            unsigned long long key = 0;
            #pragma unroll 1
            for (int i = tid; i < cs; i += FPS_T) {
                float4 q = cxyz[i];
                float dx = q.x - lx, dy = q.y - ly, dz = q.z - lz;
                float d = (dx*dx + dy*dy) + dz*dz;
                float prev = (k == 1) ? 1e10f : dm[i];
                float nd = fminf(prev, d);
                dm[i] = nd;
                unsigned long long kk =
                    ((unsigned long long)__float_as_uint(nd) << 32) | (unsigned)(~(unsigned)i);
                if (kk > key) key = kk;
            }
            key = wave_max_u64_dpp(key);
            int par = k & 1;
            if (lane == 63) skey[par][wid] = key;
            __syncthreads();
            unsigned long long q0 = skey[par][0], q1 = skey[par][1];
            unsigned long long q2 = skey[par][2], q3 = skey[par][3];
            unsigned long long q4 = skey[par][4], q5 = skey[par][5];
            unsigned long long q6 = skey[par][6], q7 = skey[par][7];
            q0 = (q1 > q0) ? q1 : q0;
            q2 = (q3 > q2) ? q3 : q2;
            q4 = (q5 > q4) ? q5 : q4;
            q6 = (q7 > q6) ? q7 : q6;
            q0 = (q2 > q0) ? q2 : q0;
            q4 = (q6 > q4) ? q6 : q4;
            unsigned long long bk = (q4 > q0) ? q4 : q0;
            int bix = (int)(~(unsigned)(bk & 0xFFFFFFFFull));
            if (tid == 0) pick_lds[k] = bix;
            float4 n4 = cxyz[bix];                            // rare path
            lx = n4.x; ly = n4.y; lz = n4.z;
        }
        __syncthreads();
        #pragma unroll 1
        for (int i = tid; i < need; i += FPS_T)
            buf[off + i] = base + pick_lds[i];
    }
}

// ----------------------------------------------------------------- out ----
__global__ void k_out(const float* __restrict__ points, const int* __restrict__ buf,
                      const int* __restrict__ comp_idx, const int* __restrict__ s_total,
                      float* __restrict__ out) {
    int i = blockIdx.x * 256 + threadIdx.x;
    if (i >= B_ * K_) return;
    int b = i / K_, j = i % K_;
    int st = s_total[b];
    int g = buf[b * K_ + (j % st)];          // compacted global slot
    int idx = comp_idx[g];                   // original point index
    const float* p = points + ((size_t)b * N_ + idx) * 3;
    float* o = out + (size_t)i * 3;
    o[0] = p[0]; o[1] = p[1]; o[2] = p[2];
}

// -------------------------------------------------------------- launch ----
extern "C" void kernel_launch(void* const* d_in, const int* in_sizes, int n_in,
                              void* d_out, int out_size, void* d_ws, size_t ws_size,
                              hipStream_t stream) {
    const float* points = (const float*)d_in[0];   // [B,N,3]
    const float* rois   = (const float*)d_in[1];   // [B,M,7]
    float* out = (float*)d_out;                    // [B,K,3]

    char* w = (char*)d_ws;
    auto carve = [&](size_t bytes) -> char* {
        char* p = w; w += (bytes + 255) & ~(size_t)255; return p;
    };
    int*    sec_id   = (int*)   carve((size_t)B_ * N_ * sizeof(int));
    int*    blkcnt   = (int*)   carve((size_t)B_ * NBLK * 8 * sizeof(int));
    int*    bbase    = (int*)   carve((size_t)B_ * NBLK * 6 * sizeof(int));
    int*    cnt      = (int*)   carve((size_t)B_ * 8 * sizeof(int));
    int*    offv     = (int*)   carve((size_t)B_ * 6 * sizeof(int));
    int*    n_needed = (int*)   carve((size_t)B_ * 6 * sizeof(int));
    int*    sec_base = (int*)   carve((size_t)B_ * 6 * sizeof(int));
    int*    s_total  = (int*)   carve((size_t)B_ * sizeof(int));
    int*    buf      = (int*)   carve((size_t)B_ * K_ * sizeof(int));
    int*    comp_idx = (int*)   carve((size_t)B_ * N_ * sizeof(int));
    float4* comp_xyz = (float4*)carve((size_t)B_ * N_ * sizeof(float4));
    float*  dmin_g   = (float*) carve((size_t)B_ * N_ * sizeof(float));

    hipLaunchKernelGGL(k_classify, dim3(B_ * NBLK), dim3(CT), 0, stream,
                       points, rois, sec_id, blkcnt);
    hipLaunchKernelGGL(k_plan, dim3(1), dim3(64), 0, stream,
                       blkcnt, bbase, cnt, offv, n_needed, sec_base, s_total);
    hipLaunchKernelGGL(k_compact, dim3(B_ * NBLK), dim3(CT), 0, stream,
                       points, sec_id, sec_base, bbase, comp_idx, comp_xyz);
    hipLaunchKernelGGL(k_fps, dim3(B_ * S_), dim3(FPS_T), 0, stream,
                       cnt, sec_base, offv, n_needed, comp_xyz, dmin_g, buf);
    hipLaunchKernelGGL(k_out, dim3((B_ * K_ + 255) / 256), dim3(256), 0, stream,
                       points, buf, comp_idx, s_total, out);
}